// Round 7
// baseline (348.041 us; speedup 1.0000x reference)
//
#include <hip/hip_runtime.h>
#include <math.h>

#define Bn 8
#define Cn 64
#define Hn 128
#define Wn 128
#define HWn (Hn * Wn)

// weight fragment regions (shorts)
#define WOM_OFF 0
#define WDC_OFF 18432
#define WC_OFF 55296

typedef __attribute__((ext_vector_type(8))) short short8;
typedef __attribute__((ext_vector_type(4))) float floatx4;
typedef __attribute__((ext_vector_type(2))) float float2v;

__device__ __forceinline__ float bf2f(short s) {
  return __uint_as_float(((unsigned)(unsigned short)s) << 16);
}
__device__ __forceinline__ short f2bf(float f) {
  unsigned u = __float_as_uint(f);
  u += 0x7fff + ((u >> 16) & 1);  // RNE
  return (short)(u >> 16);
}

// async global->LDS 16B per lane; dst slots must be lane-contiguous.
__device__ __forceinline__ void gl_lds16(const short* g, short* l) {
  __builtin_amdgcn_global_load_lds(
      (const __attribute__((address_space(1))) unsigned int*)(const void*)g,
      (__attribute__((address_space(3))) unsigned int*)(void*)l, 16, 0, 0);
}
// stage n16 16B-units (fire-and-forget; complete at next __syncthreads)
__device__ __forceinline__ void stage_async(const short* src, short* dst,
                                            int n16, int tid) {
  for (int i = tid; i < n16; i += 256) gl_lds16(src + i * 8, dst + i * 8);
}

// ---------------------------------------------------------------------------
// Prep 1: weights -> bf16 MFMA-A-fragment order (1KB per wave-frag).
// ---------------------------------------------------------------------------
__global__ __launch_bounds__(256) void k_prep_w(
    const float* __restrict__ w_om, const float* __restrict__ w_dc,
    const float* __restrict__ w_c, short* __restrict__ wt) {
  int idx = blockIdx.x * 256 + threadIdx.x;
  if (idx >= 92160) return;
  float v;
  if (idx < WDC_OFF) {  // om region, MT=2 (M=32)
    int e = idx;
    int elem = e & 7, lane = (e >> 3) & 63, mt = (e >> 9) & 1, t = e >> 10;
    int kk = t % 9, cc = t / 9;
    int row = mt * 16 + (lane & 15);
    int cin = cc * 32 + (lane >> 4) * 8 + elem;
    v = (row < 27) ? w_om[(row * 64 + cin) * 9 + kk] : 0.f;
  } else {  // dc / c regions, MT=4 (M=64)
    int e = (idx < WC_OFF) ? idx - WDC_OFF : idx - WC_OFF;
    const float* src = (idx < WC_OFF) ? w_dc : w_c;
    int elem = e & 7, lane = (e >> 3) & 63, mt = (e >> 9) & 3, t = e >> 11;
    int kk = t % 9, cc = t / 9;
    int row = mt * 16 + (lane & 15);
    int cin = cc * 32 + (lane >> 4) * 8 + elem;
    v = src[(row * 64 + cin) * 9 + kk];
  }
  wt[idx] = f2bf(v);
}

// ---------------------------------------------------------------------------
// Prep 2: x fp32 NCHW -> bf16 channels-last xT[b][h][w][64] (128B records).
// ---------------------------------------------------------------------------
__global__ __launch_bounds__(256) void k_prep_x(const float* __restrict__ x,
                                                short* __restrict__ xT) {
  __shared__ float tile[64][129];
  const int bid = blockIdx.x;
  const int b = bid & 7, h = bid >> 3;
  const int tid = threadIdx.x;
  const float* xb = x + (size_t)b * 64 * HWn + h * Wn;
  for (int i = tid; i < 8192; i += 256) {
    int c = i >> 7, w = i & 127;
    tile[c][w] = xb[c * HWn + w];
  }
  __syncthreads();
  short* dst = xT + ((size_t)(b * Hn + h) * Wn) * 64;
  for (int i = tid; i < 2048; i += 256) {
    int w = i >> 4, c4 = (i & 15) * 4;
    short4 o;
    o.x = f2bf(tile[c4 + 0][w]);
    o.y = f2bf(tile[c4 + 1][w]);
    o.z = f2bf(tile[c4 + 2][w]);
    o.w = f2bf(tile[c4 + 3][w]);
    *(short4*)(dst + (size_t)w * 64 + c4) = o;
  }
}

// ---------------------------------------------------------------------------
// Fused conv_om + deformable conv. Decoupled gather/MFMA passes, register
// B-sets, async weight staging. LDS 44KB -> 3 blocks/CU.
// ---------------------------------------------------------------------------
__global__ __launch_bounds__(256, 3) void k_omdef(
    const short* __restrict__ xT, const short* __restrict__ wt,
    const float* __restrict__ b_om, const float* __restrict__ b_dc,
    short* __restrict__ actT) {
  __shared__ __attribute__((aligned(16))) short lw[18432];  // 36KB A-stage
  __shared__ float som[27 * 66];                            // 7.1KB

  const int bid = blockIdx.x;
  const int b = bid & 7;
  const int r = bid >> 3;
  const int h = r >> 1, w0 = (r & 1) * 64;
  const int tid = threadIdx.x;
  const int wave = tid >> 6, lane = tid & 63, quad = lane >> 4, lr = lane & 15;
  const short* xb = xT + (size_t)b * HWn * 64;
  const int pxl = wave * 16 + lr;
  const int gxp = w0 + pxl;
  const floatx4 zf = {0.f, 0.f, 0.f, 0.f};
  const short8 z8 = {0, 0, 0, 0, 0, 0, 0, 0};

  // issue om weight stage (async; completes at first sync)
  stage_async(wt + WOM_OFF, lw, 2304, tid);

  // ---- phase-1 B-set: 18 independent direct loads into registers ----
  short8 Bom[18];
#pragma unroll
  for (int kk = 0; kk < 9; ++kk) {
    int ky = kk / 3, kx = kk - ky * 3;
    int gy = h + ky - 1, gx = gxp + kx - 1;
    bool ok = ((unsigned)gy < (unsigned)Hn) && ((unsigned)gx < (unsigned)Wn);
    int gyc = min(max(gy, 0), Hn - 1), gxc = min(max(gx, 0), Wn - 1);
    const short* rec = xb + (size_t)(gyc * Wn + gxc) * 64 + quad * 8;
    short8 v0 = *(const short8*)rec;
    short8 v1 = *(const short8*)(rec + 32);
    Bom[kk * 2 + 0] = ok ? v0 : z8;
    Bom[kk * 2 + 1] = ok ? v1 : z8;
  }
  __syncthreads();  // om weights staged

  // ---- phase-1 MFMA pass ----
  floatx4 aco[2] = {zf, zf};
#pragma unroll
  for (int kk = 0; kk < 9; ++kk) {
#pragma unroll
    for (int cc = 0; cc < 2; ++cc) {
      short8 a0 = *(const short8*)&lw[((cc * 9 + kk) * 2 + 0) * 512 + lane * 8];
      short8 a1 = *(const short8*)&lw[((cc * 9 + kk) * 2 + 1) * 512 + lane * 8];
      aco[0] = __builtin_amdgcn_mfma_f32_16x16x32_bf16(a0, Bom[kk * 2 + cc], aco[0], 0, 0, 0);
      aco[1] = __builtin_amdgcn_mfma_f32_16x16x32_bf16(a1, Bom[kk * 2 + cc], aco[1], 0, 0, 0);
    }
  }
  // om epilogue -> som
#pragma unroll
  for (int mt = 0; mt < 2; ++mt) {
#pragma unroll
    for (int rr = 0; rr < 4; ++rr) {
      int co = mt * 16 + quad * 4 + rr;
      if (co < 27) {
        float v = aco[mt][rr] + b_om[co];
        if (co >= 18) v = 2.f / (1.f + expf(-v));
        som[co * 66 + pxl] = v;
      }
    }
  }
  __syncthreads();  // som ready; om lw reads done

  // issue dc cc0 weight stage (async; overlaps phase A)
  stage_async(wt + WDC_OFF, lw, 2304, tid);

  // ---- phase A: per-lane bilinear params for its pixel (all 9 taps) ----
  unsigned qa01[9], qa23[9], qw01[9], qw23[9];
#pragma unroll
  for (int k = 0; k < 9; ++k) {
    float offy = som[(2 * k) * 66 + pxl];
    float offx = som[(2 * k + 1) * 66 + pxl];
    float m = som[(18 + k) * 66 + pxl];
    float py = (float)(h - 1 + (k / 3)) + offy;
    float px_ = (float)(gxp - 1 + (k % 3)) + offx;
    float fy = floorf(py), fx = floorf(px_);
    float ly = py - fy, lx = px_ - fx;
    int iy0 = (int)fy, ix0 = (int)fx;
    int iy1 = iy0 + 1, ix1 = ix0 + 1;
    bool vy0 = (iy0 >= 0) && (iy0 < Hn);
    bool vy1 = (iy1 >= 0) && (iy1 < Hn);
    bool vx0 = (ix0 >= 0) && (ix0 < Wn);
    bool vx1 = (ix1 >= 0) && (ix1 < Wn);
    unsigned cy0 = (unsigned)min(max(iy0, 0), Hn - 1);
    unsigned cy1 = (unsigned)min(max(iy1, 0), Hn - 1);
    unsigned cx0 = (unsigned)min(max(ix0, 0), Wn - 1);
    unsigned cx1 = (unsigned)min(max(ix1, 0), Wn - 1);
    qa01[k] = (cy0 * Wn + cx0) | ((cy0 * Wn + cx1) << 16);
    qa23[k] = (cy1 * Wn + cx0) | ((cy1 * Wn + cx1) << 16);
    float u0 = (vy0 && vx0) ? (1.f - ly) * (1.f - lx) * m : 0.f;
    float u1 = (vy0 && vx1) ? (1.f - ly) * lx * m : 0.f;
    float u2 = (vy1 && vx0) ? ly * (1.f - lx) * m : 0.f;
    float u3 = (vy1 && vx1) ? ly * lx * m : 0.f;
    qw01[k] = (unsigned)(unsigned short)f2bf(u0) |
              ((unsigned)(unsigned short)f2bf(u1) << 16);
    qw23[k] = (unsigned)(unsigned short)f2bf(u2) |
              ((unsigned)(unsigned short)f2bf(u3) << 16);
  }
  __syncthreads();  // dc cc0 staged; som reads done

  // ---- phase 2: per cc-half {gather pass -> Bset regs; MFMA pass} ----
  floatx4 acc[4] = {zf, zf, zf, zf};
  for (int cc = 0; cc < 2; ++cc) {
    if (cc) {
      __syncthreads();  // cc0 lw reads done
      stage_async(wt + WDC_OFF + 18432, lw, 2304, tid);  // overlaps gather
    }
    const short* xbc = xb + cc * 32 + quad * 8;
    short8 Bset[9];
#pragma unroll
    for (int k = 0; k < 9; ++k) {
      unsigned a01 = qa01[k], a23 = qa23[k];
      short8 q0 = *(const short8*)(xbc + (size_t)(a01 & 0xFFFFu) * 64);
      short8 q1 = *(const short8*)(xbc + (size_t)(a01 >> 16) * 64);
      short8 q2 = *(const short8*)(xbc + (size_t)(a23 & 0xFFFFu) * 64);
      short8 q3 = *(const short8*)(xbc + (size_t)(a23 >> 16) * 64);
      float2v u0 = {__uint_as_float(qw01[k] << 16), __uint_as_float(qw01[k] << 16)};
      float2v u1 = {__uint_as_float(qw01[k] & 0xFFFF0000u), __uint_as_float(qw01[k] & 0xFFFF0000u)};
      float2v u2 = {__uint_as_float(qw23[k] << 16), __uint_as_float(qw23[k] << 16)};
      float2v u3 = {__uint_as_float(qw23[k] & 0xFFFF0000u), __uint_as_float(qw23[k] & 0xFFFF0000u)};
      const unsigned* d0 = (const unsigned*)&q0;
      const unsigned* d1 = (const unsigned*)&q1;
      const unsigned* d2 = (const unsigned*)&q2;
      const unsigned* d3 = (const unsigned*)&q3;
      short8 o;
      unsigned* od = (unsigned*)&o;
#pragma unroll
      for (int j = 0; j < 4; ++j) {
        float2v f0 = {__uint_as_float(d0[j] << 16), __uint_as_float(d0[j] & 0xFFFF0000u)};
        float2v f1 = {__uint_as_float(d1[j] << 16), __uint_as_float(d1[j] & 0xFFFF0000u)};
        float2v f2 = {__uint_as_float(d2[j] << 16), __uint_as_float(d2[j] & 0xFFFF0000u)};
        float2v f3 = {__uint_as_float(d3[j] << 16), __uint_as_float(d3[j] & 0xFFFF0000u)};
        float2v s = f0 * u0 + f1 * u1 + f2 * u2 + f3 * u3;
        unsigned lo = __float_as_uint(s.x) + 0x8000u;
        unsigned hi = __float_as_uint(s.y) + 0x8000u;
        od[j] = __builtin_amdgcn_perm(hi, lo, 0x07060302);
      }
      Bset[k] = o;
    }
    if (cc) __syncthreads();  // cc1 weights staged
#pragma unroll
    for (int k = 0; k < 9; ++k) {
#pragma unroll
      for (int mt = 0; mt < 4; ++mt) {
        short8 a = *(const short8*)&lw[(k * 4 + mt) * 512 + lane * 8];
        acc[mt] = __builtin_amdgcn_mfma_f32_16x16x32_bf16(a, Bset[k], acc[mt], 0, 0, 0);
      }
    }
  }

  // epilogue: bias + leaky ReLU -> actT[b][h][w][64]
  short* ab = actT + ((size_t)(b * Hn + h) * Wn + w0) * 64;
#pragma unroll
  for (int mt = 0; mt < 4; ++mt) {
    int c0 = mt * 16 + quad * 4;
    short4 o;
    float v;
    v = acc[mt][0] + b_dc[c0 + 0]; o.x = f2bf(v > 0.f ? v : 0.2f * v);
    v = acc[mt][1] + b_dc[c0 + 1]; o.y = f2bf(v > 0.f ? v : 0.2f * v);
    v = acc[mt][2] + b_dc[c0 + 2]; o.z = f2bf(v > 0.f ? v : 0.2f * v);
    v = acc[mt][3] + b_dc[c0 + 3]; o.w = f2bf(v > 0.f ? v : 0.2f * v);
    *(short4*)(ab + (size_t)pxl * 64 + c0) = o;
  }
}

// ---------------------------------------------------------------------------
// conv_out: register B-sets + async staging; LDS-transposed coalesced
// epilogue with residual. LDS 36KB -> 4 blocks/CU.
// ---------------------------------------------------------------------------
__global__ __launch_bounds__(256, 4) void k_conv_out(
    const short* __restrict__ actT, const short* __restrict__ wt,
    const float* __restrict__ b_c, const float* __restrict__ x,
    float* __restrict__ out) {
  __shared__ __attribute__((aligned(16))) short lw[18432];  // 36KB

  const int bid = blockIdx.x;
  const int b = bid & 7;
  const int r = bid >> 3;
  const int h = r >> 1, w0 = (r & 1) * 64;
  const int tid = threadIdx.x;
  const int wave = tid >> 6, lane = tid & 63, quad = lane >> 4, lr = lane & 15;
  const short* ab = actT + (size_t)b * HWn * 64;
  const int pxl = wave * 16 + lr;
  const int gxp = w0 + pxl;
  const floatx4 zf = {0.f, 0.f, 0.f, 0.f};
  const short8 z8 = {0, 0, 0, 0, 0, 0, 0, 0};

  stage_async(wt + WC_OFF, lw, 2304, tid);

  floatx4 acc[4] = {zf, zf, zf, zf};
  for (int cc = 0; cc < 2; ++cc) {
    if (cc) {
      __syncthreads();  // cc0 lw reads done
      stage_async(wt + WC_OFF + 18432, lw, 2304, tid);
    }
    const short* abc = ab + cc * 32 + quad * 8;
    short8 Bc[9];
#pragma unroll
    for (int kk = 0; kk < 9; ++kk) {
      int ky = kk / 3, kx = kk - ky * 3;
      int gy = h + ky - 1, gx = gxp + kx - 1;
      bool ok = ((unsigned)gy < (unsigned)Hn) && ((unsigned)gx < (unsigned)Wn);
      int gyc = min(max(gy, 0), Hn - 1), gxc = min(max(gx, 0), Wn - 1);
      short8 v = *(const short8*)(abc + (size_t)(gyc * Wn + gxc) * 64);
      Bc[kk] = ok ? v : z8;
    }
    __syncthreads();  // weights for this cc staged
#pragma unroll
    for (int kk = 0; kk < 9; ++kk) {
#pragma unroll
      for (int mt = 0; mt < 4; ++mt) {
        short8 a = *(const short8*)&lw[(kk * 4 + mt) * 512 + lane * 8];
        acc[mt] = __builtin_amdgcn_mfma_f32_16x16x32_bf16(a, Bc[kk], acc[mt], 0, 0, 0);
      }
    }
  }

  // early residual loads (coalesced), overlap with transpose
  const int row = tid >> 2, seg = tid & 3;
  const size_t gbase = ((size_t)(b * 64 + row) * Hn + h) * Wn + w0 + seg * 16;
  floatx4 xr[4];
#pragma unroll
  for (int j = 0; j < 4; ++j) xr[j] = *(const floatx4*)(x + gbase + j * 4);

  __syncthreads();  // all lw A-reads done; reuse as fp32 tile
  float* ot = (float*)lw;
#pragma unroll
  for (int mt = 0; mt < 4; ++mt) {
#pragma unroll
    for (int rr = 0; rr < 4; ++rr) {
      ot[(mt * 16 + quad * 4 + rr) * 66 + pxl] = acc[mt][rr];
    }
  }
  __syncthreads();

  const float bias = b_c[row];
  float* op = out + gbase;
#pragma unroll
  for (int j = 0; j < 4; ++j) {
    floatx4 t = *(const floatx4*)&ot[row * 66 + seg * 16 + j * 4];
    t = t + xr[j];
    t[0] += bias; t[1] += bias; t[2] += bias; t[3] += bias;
    *(floatx4*)&op[j * 4] = t;
  }
}

// ---------------------------------------------------------------------------
extern "C" void kernel_launch(void* const* d_in, const int* in_sizes, int n_in,
                              void* d_out, int out_size, void* d_ws,
                              size_t ws_size, hipStream_t stream) {
  const float* x = (const float*)d_in[0];
  const float* w_om = (const float*)d_in[1];
  const float* b_om = (const float*)d_in[2];
  const float* w_dc = (const float*)d_in[3];
  const float* b_dc = (const float*)d_in[4];
  const float* w_c = (const float*)d_in[5];
  const float* b_c = (const float*)d_in[6];
  float* out = (float*)d_out;

  // ws: xT bf16 (16.8 MB) | actT bf16 (16.8 MB) | weight frags (184 KB)
  short* xT = (short*)d_ws;
  short* actT = xT + (size_t)Bn * HWn * 64;
  short* wt = actT + (size_t)Bn * HWn * 64;

  k_prep_w<<<dim3(360), 256, 0, stream>>>(w_om, w_dc, w_c, wt);
  k_prep_x<<<dim3(1024), 256, 0, stream>>>(x, xT);
  k_omdef<<<dim3(2048), 256, 0, stream>>>(xT, wt, b_om, b_dc, actT);
  k_conv_out<<<dim3(2048), 256, 0, stream>>>(actT, wt, b_c, x, out);
}

// Round 8
// 278.971 us; speedup vs baseline: 1.2476x; 1.2476x over previous
//
#include <hip/hip_runtime.h>
#include <math.h>

#define Bn 8
#define Cn 64
#define Hn 128
#define Wn 128
#define HWn (Hn * Wn)

// weight fragment regions (shorts)
#define WOM_OFF 0
#define WDC_OFF 18432
#define WC_OFF 55296

typedef __attribute__((ext_vector_type(8))) short short8;
typedef __attribute__((ext_vector_type(4))) float floatx4;
typedef __attribute__((ext_vector_type(2))) float float2v;

__device__ __forceinline__ float bf2f(short s) {
  return __uint_as_float(((unsigned)(unsigned short)s) << 16);
}
__device__ __forceinline__ short f2bf(float f) {
  unsigned u = __float_as_uint(f);
  u += 0x7fff + ((u >> 16) & 1);  // RNE
  return (short)(u >> 16);
}

// async global->LDS 16B per lane; dst slots lane-contiguous.
__device__ __forceinline__ void gl_lds16(const short* g, short* l) {
  __builtin_amdgcn_global_load_lds(
      (const __attribute__((address_space(1))) unsigned int*)(const void*)g,
      (__attribute__((address_space(3))) unsigned int*)(void*)l, 16, 0, 0);
}
__device__ __forceinline__ void stage_async(const short* src, short* dst,
                                            int n16, int tid) {
  for (int i = tid; i < n16; i += 256) gl_lds16(src + i * 8, dst + i * 8);
}

// packed bilinear blend of 4 corner short8s -> bf16 short8
__device__ __forceinline__ short8 blend4(short8 q0, short8 q1, short8 q2,
                                         short8 q3, unsigned w01,
                                         unsigned w23) {
  float2v u0 = {__uint_as_float(w01 << 16), __uint_as_float(w01 << 16)};
  float2v u1 = {__uint_as_float(w01 & 0xFFFF0000u),
                __uint_as_float(w01 & 0xFFFF0000u)};
  float2v u2 = {__uint_as_float(w23 << 16), __uint_as_float(w23 << 16)};
  float2v u3 = {__uint_as_float(w23 & 0xFFFF0000u),
                __uint_as_float(w23 & 0xFFFF0000u)};
  const unsigned* d0 = (const unsigned*)&q0;
  const unsigned* d1 = (const unsigned*)&q1;
  const unsigned* d2 = (const unsigned*)&q2;
  const unsigned* d3 = (const unsigned*)&q3;
  short8 o;
  unsigned* od = (unsigned*)&o;
#pragma unroll
  for (int j = 0; j < 4; ++j) {
    float2v f0 = {__uint_as_float(d0[j] << 16),
                  __uint_as_float(d0[j] & 0xFFFF0000u)};
    float2v f1 = {__uint_as_float(d1[j] << 16),
                  __uint_as_float(d1[j] & 0xFFFF0000u)};
    float2v f2 = {__uint_as_float(d2[j] << 16),
                  __uint_as_float(d2[j] & 0xFFFF0000u)};
    float2v f3 = {__uint_as_float(d3[j] << 16),
                  __uint_as_float(d3[j] & 0xFFFF0000u)};
    float2v s = f0 * u0 + f1 * u1 + f2 * u2 + f3 * u3;
    unsigned lo = __float_as_uint(s.x) + 0x8000u;
    unsigned hi = __float_as_uint(s.y) + 0x8000u;
    od[j] = __builtin_amdgcn_perm(hi, lo, 0x07060302);
  }
  return o;
}

// ---------------------------------------------------------------------------
// Prep 1: weights -> bf16 MFMA-A-fragment order (1KB per wave-frag).
// ---------------------------------------------------------------------------
__global__ __launch_bounds__(256) void k_prep_w(
    const float* __restrict__ w_om, const float* __restrict__ w_dc,
    const float* __restrict__ w_c, short* __restrict__ wt) {
  int idx = blockIdx.x * 256 + threadIdx.x;
  if (idx >= 92160) return;
  float v;
  if (idx < WDC_OFF) {  // om region, MT=2 (M=32)
    int e = idx;
    int elem = e & 7, lane = (e >> 3) & 63, mt = (e >> 9) & 1, t = e >> 10;
    int kk = t % 9, cc = t / 9;
    int row = mt * 16 + (lane & 15);
    int cin = cc * 32 + (lane >> 4) * 8 + elem;
    v = (row < 27) ? w_om[(row * 64 + cin) * 9 + kk] : 0.f;
  } else {  // dc / c regions, MT=4 (M=64)
    int e = (idx < WC_OFF) ? idx - WDC_OFF : idx - WC_OFF;
    const float* src = (idx < WC_OFF) ? w_dc : w_c;
    int elem = e & 7, lane = (e >> 3) & 63, mt = (e >> 9) & 3, t = e >> 11;
    int kk = t % 9, cc = t / 9;
    int row = mt * 16 + (lane & 15);
    int cin = cc * 32 + (lane >> 4) * 8 + elem;
    v = src[(row * 64 + cin) * 9 + kk];
  }
  wt[idx] = f2bf(v);
}

// ---------------------------------------------------------------------------
// Prep 2: x fp32 NCHW -> bf16 channels-last xT[b][h][w][64] (128B records).
// ---------------------------------------------------------------------------
__global__ __launch_bounds__(256) void k_prep_x(const float* __restrict__ x,
                                                short* __restrict__ xT) {
  __shared__ float tile[64][129];
  const int bid = blockIdx.x;
  const int b = bid & 7, h = bid >> 3;
  const int tid = threadIdx.x;
  const float* xb = x + (size_t)b * 64 * HWn + h * Wn;
  for (int i = tid; i < 8192; i += 256) {
    int c = i >> 7, w = i & 127;
    tile[c][w] = xb[c * HWn + w];
  }
  __syncthreads();
  short* dst = xT + ((size_t)(b * Hn + h) * Wn) * 64;
  for (int i = tid; i < 2048; i += 256) {
    int w = i >> 4, c4 = (i & 15) * 4;
    short4 o;
    o.x = f2bf(tile[c4 + 0][w]);
    o.y = f2bf(tile[c4 + 1][w]);
    o.z = f2bf(tile[c4 + 2][w]);
    o.w = f2bf(tile[c4 + 3][w]);
    *(short4*)(dst + (size_t)w * 64 + c4) = o;
  }
}

// ---------------------------------------------------------------------------
// Fused conv_om + deformable conv. 3 barriers; phase 2 barrier-free with
// 1-deep gather prefetch. All dc weights staged to LDS once (72KB).
// LDS 78.9KB -> 2 blocks/CU; VGPR budget 256 (no spills).
// ---------------------------------------------------------------------------
__global__ __launch_bounds__(256, 2) void k_omdef(
    const short* __restrict__ xT, const short* __restrict__ wt,
    const float* __restrict__ b_om, const float* __restrict__ b_dc,
    short* __restrict__ actT) {
  __shared__ __attribute__((aligned(16))) short lw[36864];  // 72KB A-stage
  __shared__ float som[27 * 65];                            // 7.0KB

  const int bid = blockIdx.x;
  const int b = bid & 7;
  const int r = bid >> 3;
  const int h = r >> 1, w0 = (r & 1) * 64;
  const int tid = threadIdx.x;
  const int wave = tid >> 6, lane = tid & 63, quad = lane >> 4, lr = lane & 15;
  const short* xb = xT + (size_t)b * HWn * 64;
  const int pxl = wave * 16 + lr;
  const int gxp = w0 + pxl;
  const floatx4 zf = {0.f, 0.f, 0.f, 0.f};
  const short8 z8 = {0, 0, 0, 0, 0, 0, 0, 0};

  // issue om weight stage (async; completes at barrier 1)
  stage_async(wt + WOM_OFF, lw, 2304, tid);

  // phase-1 B-set: 18 independent loads into registers (budget is 256 VGPR)
  short8 Bom[18];
#pragma unroll
  for (int kk = 0; kk < 9; ++kk) {
    int ky = kk / 3, kx = kk - ky * 3;
    int gy = h + ky - 1, gx = gxp + kx - 1;
    bool ok = ((unsigned)gy < (unsigned)Hn) && ((unsigned)gx < (unsigned)Wn);
    int gyc = min(max(gy, 0), Hn - 1), gxc = min(max(gx, 0), Wn - 1);
    const short* rec = xb + (size_t)(gyc * Wn + gxc) * 64 + quad * 8;
    short8 v0 = *(const short8*)rec;
    short8 v1 = *(const short8*)(rec + 32);
    Bom[kk * 2 + 0] = ok ? v0 : z8;
    Bom[kk * 2 + 1] = ok ? v1 : z8;
  }
  __syncthreads();  // [1] om weights staged

  // phase-1 MFMA pass
  floatx4 aco[2] = {zf, zf};
#pragma unroll
  for (int kk = 0; kk < 9; ++kk) {
#pragma unroll
    for (int cc = 0; cc < 2; ++cc) {
      short8 a0 = *(const short8*)&lw[((cc * 9 + kk) * 2 + 0) * 512 + lane * 8];
      short8 a1 = *(const short8*)&lw[((cc * 9 + kk) * 2 + 1) * 512 + lane * 8];
      aco[0] = __builtin_amdgcn_mfma_f32_16x16x32_bf16(a0, Bom[kk * 2 + cc],
                                                       aco[0], 0, 0, 0);
      aco[1] = __builtin_amdgcn_mfma_f32_16x16x32_bf16(a1, Bom[kk * 2 + cc],
                                                       aco[1], 0, 0, 0);
    }
  }
  // om epilogue -> som
#pragma unroll
  for (int mt = 0; mt < 2; ++mt) {
#pragma unroll
    for (int rr = 0; rr < 4; ++rr) {
      int co = mt * 16 + quad * 4 + rr;
      if (co < 27) {
        float v = aco[mt][rr] + b_om[co];
        if (co >= 18) v = 2.f / (1.f + expf(-v));
        som[co * 65 + pxl] = v;
      }
    }
  }
  __syncthreads();  // [2] som ready; om lw reads done

  // stage ALL dc weights (72KB, async; overlaps phase A)
  stage_async(wt + WDC_OFF, lw, 4608, tid);

  // phase A: per-lane bilinear params for its pixel (9 taps) in registers
  unsigned qa01[9], qa23[9], qw01[9], qw23[9];
#pragma unroll
  for (int k = 0; k < 9; ++k) {
    float offy = som[(2 * k) * 65 + pxl];
    float offx = som[(2 * k + 1) * 65 + pxl];
    float m = som[(18 + k) * 65 + pxl];
    float py = (float)(h - 1 + (k / 3)) + offy;
    float px_ = (float)(gxp - 1 + (k % 3)) + offx;
    float fy = floorf(py), fx = floorf(px_);
    float ly = py - fy, lx = px_ - fx;
    int iy0 = (int)fy, ix0 = (int)fx;
    int iy1 = iy0 + 1, ix1 = ix0 + 1;
    bool vy0 = (iy0 >= 0) && (iy0 < Hn);
    bool vy1 = (iy1 >= 0) && (iy1 < Hn);
    bool vx0 = (ix0 >= 0) && (ix0 < Wn);
    bool vx1 = (ix1 >= 0) && (ix1 < Wn);
    unsigned cy0 = (unsigned)min(max(iy0, 0), Hn - 1);
    unsigned cy1 = (unsigned)min(max(iy1, 0), Hn - 1);
    unsigned cx0 = (unsigned)min(max(ix0, 0), Wn - 1);
    unsigned cx1 = (unsigned)min(max(ix1, 0), Wn - 1);
    qa01[k] = (cy0 * Wn + cx0) | ((cy0 * Wn + cx1) << 16);
    qa23[k] = (cy1 * Wn + cx0) | ((cy1 * Wn + cx1) << 16);
    float u0 = (vy0 && vx0) ? (1.f - ly) * (1.f - lx) * m : 0.f;
    float u1 = (vy0 && vx1) ? (1.f - ly) * lx * m : 0.f;
    float u2 = (vy1 && vx0) ? ly * (1.f - lx) * m : 0.f;
    float u3 = (vy1 && vx1) ? ly * lx * m : 0.f;
    qw01[k] = (unsigned)(unsigned short)f2bf(u0) |
              ((unsigned)(unsigned short)f2bf(u1) << 16);
    qw23[k] = (unsigned)(unsigned short)f2bf(u2) |
              ((unsigned)(unsigned short)f2bf(u3) << 16);
  }
  __syncthreads();  // [3] dc weights staged; phase 2 is barrier-free

  // phase 2: 18 iterations, 1-deep gather prefetch, no syncs
  floatx4 acc[4] = {zf, zf, zf, zf};
  short8 q[2][4];
  {
    const short* xbc = xb + quad * 8;  // cc=0, kk=0
    q[0][0] = *(const short8*)(xbc + (size_t)(qa01[0] & 0xFFFFu) * 64);
    q[0][1] = *(const short8*)(xbc + (size_t)(qa01[0] >> 16) * 64);
    q[0][2] = *(const short8*)(xbc + (size_t)(qa23[0] & 0xFFFFu) * 64);
    q[0][3] = *(const short8*)(xbc + (size_t)(qa23[0] >> 16) * 64);
  }
#pragma unroll
  for (int i = 0; i < 18; ++i) {
    const int cc = i / 9, kk = i - cc * 9;
    if (i < 17) {
      const int i1 = i + 1;
      const int cc1 = i1 / 9, kk1 = i1 - cc1 * 9;
      const short* xbc = xb + cc1 * 32 + quad * 8;
      q[i1 & 1][0] = *(const short8*)(xbc + (size_t)(qa01[kk1] & 0xFFFFu) * 64);
      q[i1 & 1][1] = *(const short8*)(xbc + (size_t)(qa01[kk1] >> 16) * 64);
      q[i1 & 1][2] = *(const short8*)(xbc + (size_t)(qa23[kk1] & 0xFFFFu) * 64);
      q[i1 & 1][3] = *(const short8*)(xbc + (size_t)(qa23[kk1] >> 16) * 64);
    }
    short8 bf = blend4(q[i & 1][0], q[i & 1][1], q[i & 1][2], q[i & 1][3],
                       qw01[kk], qw23[kk]);
#pragma unroll
    for (int mt = 0; mt < 4; ++mt) {
      short8 a = *(const short8*)&lw[((cc * 9 + kk) * 4 + mt) * 512 + lane * 8];
      acc[mt] = __builtin_amdgcn_mfma_f32_16x16x32_bf16(a, bf, acc[mt], 0, 0, 0);
    }
  }

  // epilogue: bias + leaky ReLU -> actT[b][h][w][64]
  short* ab = actT + ((size_t)(b * Hn + h) * Wn + w0) * 64;
#pragma unroll
  for (int mt = 0; mt < 4; ++mt) {
    int c0 = mt * 16 + quad * 4;
    short4 o;
    float v;
    v = acc[mt][0] + b_dc[c0 + 0]; o.x = f2bf(v > 0.f ? v : 0.2f * v);
    v = acc[mt][1] + b_dc[c0 + 1]; o.y = f2bf(v > 0.f ? v : 0.2f * v);
    v = acc[mt][2] + b_dc[c0 + 2]; o.z = f2bf(v > 0.f ? v : 0.2f * v);
    v = acc[mt][3] + b_dc[c0 + 3]; o.w = f2bf(v > 0.f ? v : 0.2f * v);
    *(short4*)(ab + (size_t)pxl * 64 + c0) = o;
  }
}

// ---------------------------------------------------------------------------
// conv_out: wave = one m-tile x 64 px. A-fragments in registers (18x short8),
// zero barriers in main loop; LDS only for the fp32 transpose epilogue.
// LDS 16.9KB; VGPR budget 256.
// ---------------------------------------------------------------------------
__global__ __launch_bounds__(256, 2) void k_conv_out(
    const short* __restrict__ actT, const short* __restrict__ wt,
    const float* __restrict__ b_c, const float* __restrict__ x,
    float* __restrict__ out) {
  __shared__ float ot[64 * 66];  // 16.9KB transpose tile

  const int bid = blockIdx.x;
  const int b = bid & 7;
  const int r = bid >> 3;
  const int h = r >> 1, w0 = (r & 1) * 64;
  const int tid = threadIdx.x;
  const int wave = tid >> 6, lane = tid & 63, quad = lane >> 4, lr = lane & 15;
  const short* ab = actT + (size_t)b * HWn * 64;
  const floatx4 zf = {0.f, 0.f, 0.f, 0.f};
  const short8 z8 = {0, 0, 0, 0, 0, 0, 0, 0};

  // A-fragments for this wave's m-tile: 18 coalesced 1KB loads -> registers
  short8 Ar[18];
#pragma unroll
  for (int i = 0; i < 18; ++i) {
    Ar[i] = *(const short8*)(wt + WC_OFF + (size_t)(i * 4 + wave) * 512 +
                             lane * 8);
  }

  floatx4 acc[4] = {zf, zf, zf, zf};
#pragma unroll
  for (int nt = 0; nt < 4; ++nt) {
    const int gxp = w0 + nt * 16 + lr;
#pragma unroll
    for (int kk = 0; kk < 9; ++kk) {
      int ky = kk / 3, kx = kk - ky * 3;
      int gy = h + ky - 1, gx = gxp + kx - 1;
      bool ok = ((unsigned)gy < (unsigned)Hn) && ((unsigned)gx < (unsigned)Wn);
      int gyc = min(max(gy, 0), Hn - 1), gxc = min(max(gx, 0), Wn - 1);
      const short* rec = ab + (size_t)(gyc * Wn + gxc) * 64 + quad * 8;
      short8 v0 = *(const short8*)rec;
      short8 v1 = *(const short8*)(rec + 32);
      v0 = ok ? v0 : z8;
      v1 = ok ? v1 : z8;
      acc[nt] = __builtin_amdgcn_mfma_f32_16x16x32_bf16(Ar[kk], v0, acc[nt], 0, 0, 0);
      acc[nt] = __builtin_amdgcn_mfma_f32_16x16x32_bf16(Ar[9 + kk], v1, acc[nt], 0, 0, 0);
    }
  }

  // transpose acc -> ot[cout][px]; this wave owns m-tile rows wave*16..+16
  __syncthreads();  // (no prior LDS use; cheap alignment barrier)
#pragma unroll
  for (int nt = 0; nt < 4; ++nt) {
#pragma unroll
    for (int rr = 0; rr < 4; ++rr) {
      ot[(wave * 16 + quad * 4 + rr) * 66 + nt * 16 + lr] = acc[nt][rr];
    }
  }
  __syncthreads();

  // coalesced epilogue: thread = (cout row, 16-px segment)
  const int row = tid >> 2, seg = tid & 3;
  const float bias = b_c[row];
  const size_t gbase = ((size_t)(b * 64 + row) * Hn + h) * Wn + w0 + seg * 16;
  const float* xr = x + gbase;
  float* op = out + gbase;
#pragma unroll
  for (int j = 0; j < 4; ++j) {
    floatx4 t = *(const floatx4*)&ot[row * 66 + seg * 16 + j * 4];
    floatx4 xv = *(const floatx4*)&xr[j * 4];
    t = t + xv;
    t[0] += bias; t[1] += bias; t[2] += bias; t[3] += bias;
    *(floatx4*)&op[j * 4] = t;
  }
}

// ---------------------------------------------------------------------------
extern "C" void kernel_launch(void* const* d_in, const int* in_sizes, int n_in,
                              void* d_out, int out_size, void* d_ws,
                              size_t ws_size, hipStream_t stream) {
  const float* x = (const float*)d_in[0];
  const float* w_om = (const float*)d_in[1];
  const float* b_om = (const float*)d_in[2];
  const float* w_dc = (const float*)d_in[3];
  const float* b_dc = (const float*)d_in[4];
  const float* w_c = (const float*)d_in[5];
  const float* b_c = (const float*)d_in[6];
  float* out = (float*)d_out;

  // ws: xT bf16 (16.8 MB) | actT bf16 (16.8 MB) | weight frags (184 KB)
  short* xT = (short*)d_ws;
  short* actT = xT + (size_t)Bn * HWn * 64;
  short* wt = actT + (size_t)Bn * HWn * 64;

  k_prep_w<<<dim3(360), 256, 0, stream>>>(w_om, w_dc, w_c, wt);
  k_prep_x<<<dim3(1024), 256, 0, stream>>>(x, xT);
  k_omdef<<<dim3(2048), 256, 0, stream>>>(xT, wt, b_om, b_dc, actT);
  k_conv_out<<<dim3(2048), 256, 0, stream>>>(actT, wt, b_c, x, out);
}